// Round 7
// baseline (1136.809 us; speedup 1.0000x reference)
//
#include <hip/hip_runtime.h>
#include <hip/hip_bf16.h>

#define T_TOK 16384
#define CDIM 3072
#define DDIM 768
#define HDIM 1024
#define NEXP 8
#define NSLOT 33792   // 32768 assignments + 8*128 padding
#define MAXTILE 264   // NSLOT/128
#define AMB_CAP 8192

typedef __attribute__((ext_vector_type(8))) short bfrag;
typedef __attribute__((ext_vector_type(4))) float f32x4;
typedef __attribute__((ext_vector_type(4))) float fvec4;

__device__ __forceinline__ unsigned short bf16_rn(float f) {
  union { float f; unsigned u; } v; v.f = f;
  unsigned r = v.u + 0x7fffu + ((v.u >> 16) & 1u);
  return (unsigned short)(r >> 16);
}
__device__ __forceinline__ float bf16_f32(unsigned short h) {
  union { unsigned u; float f; } v; v.u = ((unsigned)h) << 16;
  return v.f;
}
__device__ __forceinline__ float gelu_exact(float x) {
  return 0.5f * x * (1.0f + erff(x * 0.70710678118654752440f));
}
__device__ __forceinline__ void glds16(const void* g, void* l) {
  __builtin_amdgcn_global_load_lds((const __attribute__((address_space(1))) void*)g,
                                   (__attribute__((address_space(3))) void*)l, 16, 0, 0);
}

// ---------------- init ----------------
__global__ void k_init(int* token_list, int* counts, int* cursors, unsigned short* zero_row,
                       int* amb_count) {
  int i = blockIdx.x * 256 + threadIdx.x;
  for (int j = i; j < NSLOT; j += 64 * 256) token_list[j] = -1;
  if (i < NEXP) counts[i] = 0;
  if (i < 128) cursors[i] = 0;
  if (i == 0) *amb_count = 0;
  if (i < 1024) zero_row[i] = 0;
}

// ---------------- split hidden f32 -> hi/lo bf16 (same layout) ----------------
__global__ void k_split_hidden(const float* __restrict__ src,
                               unsigned short* __restrict__ dhi,
                               unsigned short* __restrict__ dlo) {
  size_t i = ((size_t)blockIdx.x * 256 + threadIdx.x) * 8;
  fvec4 a = *(const fvec4*)(src + i);
  fvec4 b = *(const fvec4*)(src + i + 4);
  bfrag hv, lv;
#pragma unroll
  for (int u = 0; u < 8; ++u) {
    float v = (u < 4) ? a[u] : b[u - 4];
    unsigned short h = bf16_rn(v);
    hv[u] = (short)h;
    lv[u] = (short)bf16_rn(v - bf16_f32(h));
  }
  *(bfrag*)(dhi + i) = hv;
  *(bfrag*)(dlo + i) = lv;
}

// ---------------- transpose proj_w -> hi/lo bf16 [D][C] ----------------
__global__ void k_transpose_split(const float* __restrict__ src,
                                  unsigned short* __restrict__ dhi,
                                  unsigned short* __restrict__ dlo) {
  __shared__ float tile[32][33];
  int bx = blockIdx.x;            // over DDIM/32 = 24
  int by = blockIdx.y;            // over CDIM/32 = 96
  int tx = threadIdx.x & 31, ty = threadIdx.x >> 5;  // 8 rows
#pragma unroll
  for (int i = 0; i < 4; ++i) {
    int rr = ty + 8 * i;
    tile[rr][tx] = src[(size_t)(by * 32 + rr) * DDIM + bx * 32 + tx];
  }
  __syncthreads();
#pragma unroll
  for (int i = 0; i < 4; ++i) {
    int rr = ty + 8 * i;
    float v = tile[tx][rr];
    unsigned short h = bf16_rn(v);
    float lo = v - bf16_f32(h);
    size_t idx = (size_t)(bx * 32 + rr) * CDIM + by * 32 + tx;
    dhi[idx] = h;
    dlo[idx] = bf16_rn(lo);
  }
}

// ---------------- transpose+cast f32 [Z][R][Cc] -> bf16 [Z][Cc][R] ----------------
__global__ void k_transpose_cast(const float* __restrict__ src0, unsigned short* __restrict__ dst0,
                                 int R, int Cc) {
  __shared__ float tile[32][33];
  int z = blockIdx.z;
  const float* src = src0 + (size_t)z * R * Cc;
  unsigned short* dst = dst0 + (size_t)z * R * Cc;
  int bx = blockIdx.x;            // over Cc/32
  int by = blockIdx.y;            // over R/32
  int tx = threadIdx.x & 31, ty = threadIdx.x >> 5;
#pragma unroll
  for (int i = 0; i < 4; ++i) {
    int rr = ty + 8 * i;
    tile[rr][tx] = src[(size_t)(by * 32 + rr) * Cc + bx * 32 + tx];
  }
  __syncthreads();
#pragma unroll
  for (int i = 0; i < 4; ++i) {
    int rr = ty + 8 * i;
    dst[(size_t)(bx * 32 + rr) * R + by * 32 + tx] = bf16_rn(tile[tx][rr]);
  }
}

// ---------------- GEMM1: xw = hidden * pwT^T, split-bf16 3-term, LDS double-buffer ----
// 2-phase schedule: STAGE(next) issued BEFORE compute(cur); single barrier per K-step.
__launch_bounds__(256, 2)
__global__ void k_gemm1(const unsigned short* __restrict__ Ahi,  // [T][3072] bf16
                        const unsigned short* __restrict__ Alo,
                        const unsigned short* __restrict__ BTh,  // pwT_hi [768][3072]
                        const unsigned short* __restrict__ BTl,
                        float* __restrict__ Cout)                // xw [T][768]
{
  __shared__ unsigned short sAh[8192], sAl[8192], sBh[8192], sBl[8192];  // 2 bufs each
  int tid = threadIdx.x;
  int lane = tid & 63, wave = tid >> 6;
  int id = blockIdx.x;                       // 768 blocks
  int swz = (id & 7) * 96 + (id >> 3);       // bijective XCD swizzle (768%8==0)
  int brow = swz / 6, bcol = swz % 6;
  int row0 = brow * 128, col0 = bcol * 128;
  int wm = wave >> 1, wn = wave & 1;

  f32x4 acc[4][4];
#pragma unroll
  for (int i = 0; i < 4; ++i)
#pragma unroll
    for (int j = 0; j < 4; ++j) acc[i][j] = (f32x4){0.f, 0.f, 0.f, 0.f};

  int rsel = lane & 15, kq = lane >> 4;

  auto STAGE = [&](int kt, int b) {
    int k0 = kt * 32;
    int lbase = b * 4096;
#pragma unroll
    for (int pass = 0; pass < 2; ++pass) {
      int g = pass * 256 + tid;            // granule id 0..511
      int kg = g >> 7, r = g & 127;
      size_t aoff = (size_t)(row0 + r) * CDIM + k0 + kg * 8;
      size_t boff = (size_t)(col0 + r) * CDIM + k0 + kg * 8;
      int li = lbase + (pass * 256 + wave * 64) * 8;
      glds16(Ahi + aoff, &sAh[li]);
      glds16(Alo + aoff, &sAl[li]);
      glds16(BTh + boff, &sBh[li]);
      glds16(BTl + boff, &sBl[li]);
    }
  };

  STAGE(0, 0);
  __syncthreads();   // drain prologue loads

  for (int kt = 0; kt < 96; ++kt) {
    int b = kt & 1;
    if (kt + 1 < 96) STAGE(kt + 1, b ^ 1);   // issue prefetch early
    int lb = b * 4096;
    bfrag ah[4], al[4], bh[4], bl[4];
#pragma unroll
    for (int i = 0; i < 4; ++i) {
      int ra = wm * 64 + i * 16 + rsel;
      ah[i] = *(const bfrag*)&sAh[lb + (kq * 128 + ra) * 8];
      al[i] = *(const bfrag*)&sAl[lb + (kq * 128 + ra) * 8];
      int cb = wn * 64 + i * 16 + rsel;
      bh[i] = *(const bfrag*)&sBh[lb + (kq * 128 + cb) * 8];
      bl[i] = *(const bfrag*)&sBl[lb + (kq * 128 + cb) * 8];
    }
#pragma unroll
    for (int i = 0; i < 4; ++i)
#pragma unroll
      for (int j = 0; j < 4; ++j) {
        acc[i][j] = __builtin_amdgcn_mfma_f32_16x16x32_bf16(ah[i], bh[j], acc[i][j], 0, 0, 0);
        acc[i][j] = __builtin_amdgcn_mfma_f32_16x16x32_bf16(ah[i], bl[j], acc[i][j], 0, 0, 0);
        acc[i][j] = __builtin_amdgcn_mfma_f32_16x16x32_bf16(al[i], bh[j], acc[i][j], 0, 0, 0);
      }
    __syncthreads();  // implicit vmcnt(0) drain lands AFTER MFMA: prefetch overlapped
  }

  int cc = lane & 15, rr = (lane >> 4) * 4;
#pragma unroll
  for (int i = 0; i < 4; ++i)
#pragma unroll
    for (int j = 0; j < 4; ++j)
#pragma unroll
      for (int r = 0; r < 4; ++r) {
        int row = row0 + wm * 64 + i * 16 + rr + r;
        int col = col0 + wn * 64 + j * 16 + cc;
        Cout[(size_t)row * DDIM + col] = acc[i][j][r];
      }
}

// ---------------- LN1 + GELU + router, wave-per-token ----------------
__launch_bounds__(256)
__global__ void k_ln_router(const float* __restrict__ xw, const float* __restrict__ proj_b,
                            const float* __restrict__ g1, const float* __restrict__ b1v,
                            const float* __restrict__ gate_w, const float* __restrict__ gate_b,
                            unsigned short* __restrict__ seq_b16,
                            int* __restrict__ top_i, float* __restrict__ top_w,
                            int* __restrict__ amb_list, int* __restrict__ amb_count)
{
  int lane = threadIdx.x & 63;
  int t = blockIdx.x * 4 + (threadIdx.x >> 6);
  const float* xr = xw + (size_t)t * DDIM;
  float x0[12];
  float s = 0.f, s2 = 0.f;
#pragma unroll
  for (int j = 0; j < 12; ++j) {
    int d = lane + 64 * j;
    float v = xr[d] + proj_b[d];
    x0[j] = v; s += v; s2 += v * v;
  }
#pragma unroll
  for (int o = 32; o > 0; o >>= 1) { s += __shfl_xor(s, o, 64); s2 += __shfl_xor(s2, o, 64); }
  float mu = s * (1.f / DDIM);
  float rstd = rsqrtf(s2 * (1.f / DDIM) - mu * mu + 1e-5f);
  float acc8[8];
#pragma unroll
  for (int e = 0; e < 8; ++e) acc8[e] = 0.f;
#pragma unroll
  for (int j = 0; j < 12; ++j) {
    int d = lane + 64 * j;
    float y = (x0[j] - mu) * rstd * g1[d] + b1v[d];
    float ge = gelu_exact(y);
    seq_b16[(size_t)t * DDIM + d] = bf16_rn(ge);
    const float* gw = gate_w + (size_t)d * NEXP;
#pragma unroll
    for (int e = 0; e < 8; ++e) acc8[e] += ge * gw[e];
  }
#pragma unroll
  for (int e = 0; e < 8; ++e)
#pragma unroll
    for (int o = 32; o > 0; o >>= 1) acc8[e] += __shfl_xor(acc8[e], o, 64);
  if (lane == 0) {
    float lg[8];
#pragma unroll
    for (int e = 0; e < 8; ++e) lg[e] = acc8[e] + gate_b[e];
    int i0 = 0;
    for (int e = 1; e < 8; ++e) if (lg[e] > lg[i0]) i0 = e;
    int i1 = (i0 == 0) ? 1 : 0;
    for (int e = 0; e < 8; ++e) if (e != i0 && lg[e] > lg[i1]) i1 = e;
    float l2 = -1e30f;
    for (int e = 0; e < 8; ++e) if (e != i0 && e != i1 && lg[e] > l2) l2 = lg[e];
    if (lg[i1] - l2 < 2e-4f) {
      int p = atomicAdd(amb_count, 1);
      if (p < AMB_CAP) amb_list[p] = t;
    }
    float w0 = 1.f / (1.f + expf(lg[i1] - lg[i0]));
    top_i[t * 2] = i0; top_i[t * 2 + 1] = i1;
    top_w[t * 2] = w0; top_w[t * 2 + 1] = 1.f - w0;
  }
}

// ---------------- f64 router fix for near-tie tokens (register-batched ILP) ----------------
__launch_bounds__(256, 1)
__global__ void k_router_fix(const float* __restrict__ hidden, const float* __restrict__ proj_w,
                             const float* __restrict__ proj_b, const float* __restrict__ g1,
                             const float* __restrict__ b1v, const float* __restrict__ gate_w,
                             const float* __restrict__ gate_b,
                             const int* __restrict__ amb_list, const int* __restrict__ amb_count,
                             int* __restrict__ top_i, float* __restrict__ top_w)
{
  __shared__ float hrow[CDIM];
  __shared__ double redA[4], redB[4], red8[4][8];
  int tid = threadIdx.x, lane = tid & 63, wave = tid >> 6;
  int n = *amb_count; if (n > AMB_CAP) n = AMB_CAP;
  for (int ii = blockIdx.x; ii < n; ii += gridDim.x) {
    int t = amb_list[ii];
    __syncthreads();   // guard hrow/red reuse across loop iterations
    for (int c = tid * 4; c < CDIM; c += 1024)
      *(fvec4*)&hrow[c] = *(const fvec4*)(hidden + (size_t)t * CDIM + c);
    __syncthreads();
    double a0a = 0.0, a0b = 0.0, a1a = 0.0, a1b = 0.0, a2a = 0.0, a2b = 0.0;
    for (int c0 = 0; c0 < CDIM; c0 += 16) {
      float w0r[16], w1r[16], w2r[16];
      const float* wp = proj_w + (size_t)c0 * DDIM + tid;
#pragma unroll
      for (int u = 0; u < 16; ++u) {
        w0r[u] = wp[u * DDIM];
        w1r[u] = wp[u * DDIM + 256];
        w2r[u] = wp[u * DDIM + 512];
      }
#pragma unroll
      for (int u = 0; u < 16; ++u) {
        double h = (double)hrow[c0 + u];
        if (u & 1) { a0b += h * (double)w0r[u]; a1b += h * (double)w1r[u]; a2b += h * (double)w2r[u]; }
        else       { a0a += h * (double)w0r[u]; a1a += h * (double)w1r[u]; a2a += h * (double)w2r[u]; }
      }
    }
    double x[3]; double s = 0.0, s2 = 0.0;
    x[0] = a0a + a0b + (double)proj_b[tid];
    x[1] = a1a + a1b + (double)proj_b[tid + 256];
    x[2] = a2a + a2b + (double)proj_b[tid + 512];
#pragma unroll
    for (int j = 0; j < 3; ++j) { s += x[j]; s2 += x[j] * x[j]; }
#pragma unroll
    for (int o = 32; o > 0; o >>= 1) { s += __shfl_down(s, o, 64); s2 += __shfl_down(s2, o, 64); }
    if (lane == 0) { redA[wave] = s; redB[wave] = s2; }
    __syncthreads();
    double mu = (redA[0] + redA[1] + redA[2] + redA[3]) / DDIM;
    double ms = (redB[0] + redB[1] + redB[2] + redB[3]) / DDIM;
    double rstd = 1.0 / sqrt(ms - mu * mu + 1e-5);
    double a8[8];
#pragma unroll
    for (int e = 0; e < 8; ++e) a8[e] = 0.0;
#pragma unroll
    for (int j = 0; j < 3; ++j) {
      int d = tid + 256 * j;
      double y = (x[j] - mu) * rstd * (double)g1[d] + (double)b1v[d];
      double ge = 0.5 * y * (1.0 + erf(y * 0.7071067811865475244));
#pragma unroll
      for (int e = 0; e < 8; ++e) a8[e] += ge * (double)gate_w[(size_t)d * NEXP + e];
    }
#pragma unroll
    for (int e = 0; e < 8; ++e)
#pragma unroll
      for (int o = 32; o > 0; o >>= 1) a8[e] += __shfl_down(a8[e], o, 64);
    if (lane == 0) {
#pragma unroll
      for (int e = 0; e < 8; ++e) red8[wave][e] = a8[e];
    }
    __syncthreads();
    if (tid == 0) {
      double lg[8];
#pragma unroll
      for (int e = 0; e < 8; ++e)
        lg[e] = red8[0][e] + red8[1][e] + red8[2][e] + red8[3][e] + (double)gate_b[e];
      int i0 = 0;
      for (int e = 1; e < 8; ++e) if (lg[e] > lg[i0]) i0 = e;
      int i1 = (i0 == 0) ? 1 : 0;
      for (int e = 0; e < 8; ++e) if (e != i0 && e != i1 && lg[e] > lg[i1]) i1 = e;
      double w0 = 1.0 / (1.0 + exp(lg[i1] - lg[i0]));
      top_i[t * 2] = i0; top_i[t * 2 + 1] = i1;
      top_w[t * 2] = (float)w0; top_w[t * 2 + 1] = (float)(1.0 - w0);
    }
  }
}

// ---------------- histogram of final top_i (LDS privatized) ----------------
__global__ void k_count(const int* __restrict__ top_i, int* __restrict__ counts) {
  __shared__ int h[NEXP];
  int tid = threadIdx.x;
  if (tid < NEXP) h[tid] = 0;
  __syncthreads();
  for (int i = blockIdx.x * 256 + tid; i < 2 * T_TOK; i += 64 * 256)
    atomicAdd(&h[top_i[i]], 1);
  __syncthreads();
  if (tid < NEXP) atomicAdd(&counts[tid], h[tid]);
}

// ---------------- offsets (single thread) ----------------
__global__ void k_offsets(const int* __restrict__ counts, int* __restrict__ seg_start,
                          int* __restrict__ padded_total, int* __restrict__ tile_expert) {
  if (threadIdx.x != 0 || blockIdx.x != 0) return;
  int st[NEXP], en[NEXP];
  int s = 0;
  for (int e = 0; e < NEXP; ++e) {
    st[e] = s; seg_start[e] = s;
    s += (counts[e] + 127) & ~127;
    en[e] = s;
  }
  *padded_total = s;
  int nt = s >> 7;
  for (int x = 0; x < nt; ++x) {
    int r = x << 7, e = 0;
    for (int q = 0; q < NEXP; ++q) if (r >= st[q] && r < en[q]) e = q;
    tile_expert[x] = e;
  }
}

// ---------------- scatter: block-aggregated cursors ----------------
__global__ void k_scatter(const int* __restrict__ top_i, const int* __restrict__ seg_start,
                          int* __restrict__ cursors, int* __restrict__ token_list,
                          int* __restrict__ slot_of) {
  __shared__ int lc[NEXP];
  __shared__ int lbase[NEXP];
  int tid = threadIdx.x;
  int t = blockIdx.x * 256 + tid;
  if (tid < NEXP) lc[tid] = 0;
  __syncthreads();
  int e0 = top_i[t * 2], e1 = top_i[t * 2 + 1];
  int o0 = atomicAdd(&lc[e0], 1);
  int o1 = atomicAdd(&lc[e1], 1);
  __syncthreads();
  if (tid < NEXP) lbase[tid] = atomicAdd(&cursors[tid << 4], lc[tid]);
  __syncthreads();
  int p0 = seg_start[e0] + lbase[e0] + o0;
  int p1 = seg_start[e1] + lbase[e1] + o1;
  token_list[p0] = t;
  token_list[p1] = t;
  slot_of[t * 2] = p0;
  slot_of[t * 2 + 1] = p1;
}

// ---------------- GEMM2: h = gelu(gather(seq)*w1 + b1), bf16, dbuf ----------------
__launch_bounds__(256, 4)
__global__ void k_gemm2(const unsigned short* __restrict__ Abase,  // seq_bf16 [T][768]
                        const unsigned short* __restrict__ w1T,    // [E][1024][768]
                        const float* __restrict__ b1,              // [E][1024]
                        const int* __restrict__ token_list,
                        const int* __restrict__ tile_expert,
                        const int* __restrict__ padded_total,
                        const unsigned short* __restrict__ zero_row,
                        unsigned short* __restrict__ hbuf)         // [NSLOT][1024]
{
  int by = blockIdx.y;
  if (by * 128 >= *padded_total) return;
  int bx = blockIdx.x;                    // 0..7
  int e = tile_expert[by];
  __shared__ unsigned short sA[8192], sB[8192];   // 2 bufs each
  __shared__ int tk[128];
  int tid = threadIdx.x, lane = tid & 63, wave = tid >> 6;
  if (tid < 128) tk[tid] = token_list[by * 128 + tid];
  __syncthreads();
  int col0 = bx * 128;
  int wm = wave >> 1, wn = wave & 1;
  f32x4 acc[4][4];
#pragma unroll
  for (int i = 0; i < 4; ++i)
#pragma unroll
    for (int j = 0; j < 4; ++j) acc[i][j] = (f32x4){0.f, 0.f, 0.f, 0.f};
  const unsigned short* Bbase = w1T + ((size_t)e * HDIM + col0) * DDIM;
  int rsel = lane & 15, kq = lane >> 4;

  auto STAGE = [&](int kt, int b) {
    int k0 = kt * 32;
    int lbase2 = b * 4096;
#pragma unroll
    for (int pass = 0; pass < 2; ++pass) {
      int g = pass * 256 + tid;
      int kg = g >> 7, r = g & 127;
      int tok = tk[r];
      const unsigned short* asrc =
          (tok >= 0) ? (Abase + (size_t)tok * DDIM + k0 + kg * 8) : zero_row;
      int li = lbase2 + (pass * 256 + wave * 64) * 8;
      glds16(asrc, &sA[li]);
      glds16(Bbase + (size_t)r * DDIM + k0 + kg * 8, &sB[li]);
    }
  };

  STAGE(0, 0);
  __syncthreads();
  for (int kt = 0; kt < 24; ++kt) {
    int b = kt & 1;
    if (kt + 1 < 24) STAGE(kt + 1, b ^ 1);
    int lb = b * 4096;
    bfrag af[4], bf[4];
#pragma unroll
    for (int i = 0; i < 4; ++i) {
      af[i] = *(const bfrag*)&sA[lb + (kq * 128 + wm * 64 + i * 16 + rsel) * 8];
      bf[i] = *(const bfrag*)&sB[lb + (kq * 128 + wn * 64 + i * 16 + rsel) * 8];
    }
#pragma unroll
    for (int i = 0; i < 4; ++i)
#pragma unroll
      for (int j = 0; j < 4; ++j)
        acc[i][j] = __builtin_amdgcn_mfma_f32_16x16x32_bf16(af[i], bf[j], acc[i][j], 0, 0, 0);
    __syncthreads();
  }
  int cc = lane & 15, rr = (lane >> 4) * 4;
#pragma unroll
  for (int i = 0; i < 4; ++i)
#pragma unroll
    for (int j = 0; j < 4; ++j)
#pragma unroll
      for (int r = 0; r < 4; ++r) {
        int row = by * 128 + wm * 64 + i * 16 + rr + r;
        int col = col0 + wn * 64 + j * 16 + cc;
        float x = acc[i][j][r] + b1[(size_t)e * HDIM + col];
        hbuf[(size_t)row * HDIM + col] = bf16_rn(gelu_exact(x));
      }
}

// ---------------- GEMM3: eo = h*w2 + b2, bf16 -> f32, dbuf ----------------
__launch_bounds__(256, 4)
__global__ void k_gemm3(const unsigned short* __restrict__ hbuf,  // [NSLOT][1024]
                        const unsigned short* __restrict__ w2T,   // [E][768][1024]
                        const float* __restrict__ b2,              // [E][768]
                        const int* __restrict__ tile_expert,
                        const int* __restrict__ padded_total,
                        float* __restrict__ eo)                   // [NSLOT][768]
{
  int by = blockIdx.y;
  if (by * 128 >= *padded_total) return;
  int bx = blockIdx.x;                    // 0..5
  int e = tile_expert[by];
  __shared__ unsigned short sA[8192], sB[8192];
  int tid = threadIdx.x, lane = tid & 63, wave = tid >> 6;
  int col0 = bx * 128;
  int wm = wave >> 1, wn = wave & 1;
  f32x4 acc[4][4];
#pragma unroll
  for (int i = 0; i < 4; ++i)
#pragma unroll
    for (int j = 0; j < 4; ++j) acc[i][j] = (f32x4){0.f, 0.f, 0.f, 0.f};
  const unsigned short* Bbase = w2T + ((size_t)e * DDIM + col0) * HDIM;
  int rsel = lane & 15, kq = lane >> 4;

  auto STAGE = [&](int kt, int b) {
    int k0 = kt * 32;
    int lbase2 = b * 4096;
#pragma unroll
    for (int pass = 0; pass < 2; ++pass) {
      int g = pass * 256 + tid;
      int kg = g >> 7, r = g & 127;
      int li = lbase2 + (pass * 256 + wave * 64) * 8;
      glds16(hbuf + (size_t)(by * 128 + r) * HDIM + k0 + kg * 8, &sA[li]);
      glds16(Bbase + (size_t)r * HDIM + k0 + kg * 8, &sB[li]);
    }
  };

  STAGE(0, 0);
  __syncthreads();
  for (int kt = 0; kt < 32; ++kt) {
    int b = kt & 1;
    if (kt + 1 < 32) STAGE(kt + 1, b ^ 1);
    int lb = b * 4096;
    bfrag af[4], bf[4];
#pragma unroll
    for (int i = 0; i < 4; ++i) {
      af[i] = *(const bfrag*)&sA[lb + (kq * 128 + wm * 64 + i * 16 + rsel) * 8];
      bf[i] = *(const bfrag*)&sB[lb + (kq * 128 + wn * 64 + i * 16 + rsel) * 8];
    }
#pragma unroll
    for (int i = 0; i < 4; ++i)
#pragma unroll
      for (int j = 0; j < 4; ++j)
        acc[i][j] = __builtin_amdgcn_mfma_f32_16x16x32_bf16(af[i], bf[j], acc[i][j], 0, 0, 0);
    __syncthreads();
  }
  int cc = lane & 15, rr = (lane >> 4) * 4;
#pragma unroll
  for (int i = 0; i < 4; ++i)
#pragma unroll
    for (int j = 0; j < 4; ++j)
#pragma unroll
      for (int r = 0; r < 4; ++r) {
        int row = by * 128 + wm * 64 + i * 16 + rr + r;
        int col = col0 + wn * 64 + j * 16 + cc;
        eo[(size_t)row * DDIM + col] = acc[i][j][r] + b2[(size_t)e * DDIM + col];
      }
}

// ---------------- combine + LN2 + classifier, wave-per-token ----------------
__launch_bounds__(256)
__global__ void k_combine(const float* __restrict__ eo, const unsigned short* __restrict__ seqb,
                          const int* __restrict__ slot_of, const float* __restrict__ top_w,
                          const float* __restrict__ g2, const float* __restrict__ b2v,
                          const float* __restrict__ cls_w, const float* __restrict__ cls_b,
                          float* __restrict__ out)
{
  int lane = threadIdx.x & 63;
  int t = blockIdx.x * 4 + (threadIdx.x >> 6);
  int s0 = slot_of[t * 2], s1 = slot_of[t * 2 + 1];
  float w0 = top_w[t * 2], w1 = top_w[t * 2 + 1];
  const float* p0 = eo + (size_t)s0 * DDIM;
  const float* p1 = eo + (size_t)s1 * DDIM;
  const unsigned short* sq = seqb + (size_t)t * DDIM;
  float m[12];
  float s = 0.f, s2 = 0.f;
#pragma unroll
  for (int j = 0; j < 12; ++j) {
    int d = lane + 64 * j;
    float v = w0 * p0[d] + w1 * p1[d] + bf16_f32(sq[d]);
    m[j] = v; s += v; s2 += v * v;
  }
#pragma unroll
  for (int o = 32; o > 0; o >>= 1) { s += __shfl_xor(s, o, 64); s2 += __shfl_xor(s2, o, 64); }
  float mu = s * (1.f / DDIM);
  float rstd = rsqrtf(s2 * (1.f / DDIM) - mu * mu + 1e-5f);
  float l0 = 0.f, l1 = 0.f;
#pragma unroll
  for (int j = 0; j < 12; ++j) {
    int d = lane + 64 * j;
    float y = (m[j] - mu) * rstd * g2[d] + b2v[d];
    l0 += y * cls_w[d * 2];
    l1 += y * cls_w[d * 2 + 1];
  }
#pragma unroll
  for (int o = 32; o > 0; o >>= 1) { l0 += __shfl_xor(l0, o, 64); l1 += __shfl_xor(l1, o, 64); }
  if (lane == 0) {
    out[(size_t)t * 2] = l0 + cls_b[0];
    out[(size_t)t * 2 + 1] = l1 + cls_b[1];
  }
}

extern "C" void kernel_launch(void* const* d_in, const int* in_sizes, int n_in,
                              void* d_out, int out_size, void* d_ws, size_t ws_size,
                              hipStream_t stream) {
  const float* hidden = (const float*)d_in[0];
  const float* proj_w = (const float*)d_in[1];
  const float* proj_b = (const float*)d_in[2];
  const float* ln1_g  = (const float*)d_in[3];
  const float* ln1_b  = (const float*)d_in[4];
  const float* gate_w = (const float*)d_in[5];
  const float* gate_b = (const float*)d_in[6];
  const float* w1     = (const float*)d_in[7];
  const float* b1     = (const float*)d_in[8];
  const float* w2     = (const float*)d_in[9];
  const float* b2     = (const float*)d_in[10];
  const float* ln2_g  = (const float*)d_in[11];
  const float* ln2_b  = (const float*)d_in[12];
  const float* cls_w  = (const float*)d_in[13];
  const float* cls_b  = (const float*)d_in[14];
  float* out = (float*)d_out;

  char* base = (char*)d_ws;
  size_t off = 0;
  auto alloc = [&](size_t b) -> void* {
    void* p = base + off;
    off += (b + 255) & ~(size_t)255;
    return p;
  };
  // permanent buffers
  unsigned short* pwT_hi = (unsigned short*)alloc((size_t)DDIM * CDIM * 2);
  unsigned short* pwT_lo = (unsigned short*)alloc((size_t)DDIM * CDIM * 2);
  unsigned short* w1T    = (unsigned short*)alloc((size_t)NEXP * HDIM * DDIM * 2);
  unsigned short* w2T    = (unsigned short*)alloc((size_t)NEXP * DDIM * HDIM * 2);
  float* xw              = (float*)alloc((size_t)T_TOK * DDIM * 4);
  int* token_list        = (int*)alloc((size_t)NSLOT * 4);
  int* counts            = (int*)alloc(256);
  int* cursors           = (int*)alloc(512);          // 8 counters, stride 16 ints
  int* seg_start         = (int*)alloc(256);
  int* padded_total      = (int*)alloc(256);
  int* tile_expert       = (int*)alloc((size_t)MAXTILE * 4);
  unsigned short* zero_row = (unsigned short*)alloc(2048);
  int* amb_count         = (int*)alloc(256);
  // aliased pool: Ahi/Alo live until k_gemm1 completes; the rest are written after.
  size_t poolBytes = 2 * (size_t)T_TOK * CDIM * 2;    // 201.3 MB
  char* pool = (char*)alloc(poolBytes);
  unsigned short* Ahi = (unsigned short*)pool;
  unsigned short* Alo = Ahi + (size_t)T_TOK * CDIM;
  size_t poff = 0;
  auto palloc = [&](size_t b) -> void* {
    void* p = pool + poff;
    poff += (b + 255) & ~(size_t)255;
    return p;
  };
  unsigned short* seqb   = (unsigned short*)palloc((size_t)T_TOK * DDIM * 2);
  int* top_i             = (int*)palloc((size_t)T_TOK * 2 * 4);
  float* top_w           = (float*)palloc((size_t)T_TOK * 2 * 4);
  int* slot_of           = (int*)palloc((size_t)T_TOK * 2 * 4);
  int* amb_list          = (int*)palloc((size_t)AMB_CAP * 4);
  unsigned short* hbuf   = (unsigned short*)palloc((size_t)NSLOT * HDIM * 2);
  float* eo              = (float*)palloc((size_t)NSLOT * DDIM * 4);
  (void)ws_size; (void)in_sizes; (void)n_in; (void)out_size;

  k_init<<<64, 256, 0, stream>>>(token_list, counts, cursors, zero_row, amb_count);
  k_split_hidden<<<(T_TOK * CDIM) / 2048, 256, 0, stream>>>(hidden, Ahi, Alo);
  k_transpose_split<<<dim3(24, 96), 256, 0, stream>>>(proj_w, pwT_hi, pwT_lo);
  k_transpose_cast<<<dim3(32, 24, 8), 256, 0, stream>>>(w1, w1T, DDIM, HDIM);
  k_transpose_cast<<<dim3(24, 32, 8), 256, 0, stream>>>(w2, w2T, HDIM, DDIM);
  k_gemm1<<<768, 256, 0, stream>>>(Ahi, Alo, pwT_hi, pwT_lo, xw);
  k_ln_router<<<T_TOK / 4, 256, 0, stream>>>(xw, proj_b, ln1_g, ln1_b, gate_w, gate_b,
                                             seqb, top_i, top_w, amb_list, amb_count);
  k_router_fix<<<256, 256, 0, stream>>>(hidden, proj_w, proj_b, ln1_g, ln1_b, gate_w, gate_b,
                                        amb_list, amb_count, top_i, top_w);
  k_count<<<64, 256, 0, stream>>>(top_i, counts);
  k_offsets<<<1, 64, 0, stream>>>(counts, seg_start, padded_total, tile_expert);
  k_scatter<<<64, 256, 0, stream>>>(top_i, seg_start, cursors, token_list, slot_of);
  k_gemm2<<<dim3(8, MAXTILE), 256, 0, stream>>>(seqb, w1T, b1, token_list, tile_expert,
                                                padded_total, zero_row, hbuf);
  k_gemm3<<<dim3(6, MAXTILE), 256, 0, stream>>>(hbuf, w2T, b2, tile_expert, padded_total, eo);
  k_combine<<<T_TOK / 4, 256, 0, stream>>>(eo, seqb, slot_of, top_w, ln2_g, ln2_b,
                                           cls_w, cls_b, out);
}

// Round 8
// 1040.844 us; speedup vs baseline: 1.0922x; 1.0922x over previous
//
#include <hip/hip_runtime.h>
#include <hip/hip_bf16.h>

#define T_TOK 16384
#define CDIM 3072
#define DDIM 768
#define HDIM 1024
#define NEXP 8
#define NSLOT 33792   // 32768 assignments + 8*128 padding
#define MAXTILE 264   // NSLOT/128
#define AMB_CAP 8192

typedef __attribute__((ext_vector_type(8))) short bfrag;
typedef __attribute__((ext_vector_type(4))) float f32x4;
typedef __attribute__((ext_vector_type(4))) float fvec4;

__device__ __forceinline__ unsigned short bf16_rn(float f) {
  union { float f; unsigned u; } v; v.f = f;
  unsigned r = v.u + 0x7fffu + ((v.u >> 16) & 1u);
  return (unsigned short)(r >> 16);
}
__device__ __forceinline__ float bf16_f32(unsigned short h) {
  union { unsigned u; float f; } v; v.u = ((unsigned)h) << 16;
  return v.f;
}
__device__ __forceinline__ float gelu_exact(float x) {
  return 0.5f * x * (1.0f + erff(x * 0.70710678118654752440f));
}
__device__ __forceinline__ void glds16(const void* g, void* l) {
  __builtin_amdgcn_global_load_lds((const __attribute__((address_space(1))) void*)g,
                                   (__attribute__((address_space(3))) void*)l, 16, 0, 0);
}

// ---------------- init ----------------
__global__ void k_init(int* token_list, int* counts, int* cursors, unsigned short* zero_row,
                       int* amb_count, int* amb2_count) {
  int i = blockIdx.x * 256 + threadIdx.x;
  for (int j = i; j < NSLOT; j += 64 * 256) token_list[j] = -1;
  if (i < NEXP) counts[i] = 0;
  if (i < 128) cursors[i] = 0;
  if (i == 0) { *amb_count = 0; *amb2_count = 0; }
  if (i < 1024) zero_row[i] = 0;
}

// ---------------- split hidden f32 -> hi/lo bf16 (same layout) ----------------
__global__ void k_split_hidden(const float* __restrict__ src,
                               unsigned short* __restrict__ dhi,
                               unsigned short* __restrict__ dlo) {
  size_t i = ((size_t)blockIdx.x * 256 + threadIdx.x) * 8;
  fvec4 a = *(const fvec4*)(src + i);
  fvec4 b = *(const fvec4*)(src + i + 4);
  bfrag hv, lv;
#pragma unroll
  for (int u = 0; u < 8; ++u) {
    float v = (u < 4) ? a[u] : b[u - 4];
    unsigned short h = bf16_rn(v);
    hv[u] = (short)h;
    lv[u] = (short)bf16_rn(v - bf16_f32(h));
  }
  *(bfrag*)(dhi + i) = hv;
  *(bfrag*)(dlo + i) = lv;
}

// ---------------- transpose proj_w -> hi/lo bf16 [D][C] ----------------
__global__ void k_transpose_split(const float* __restrict__ src,
                                  unsigned short* __restrict__ dhi,
                                  unsigned short* __restrict__ dlo) {
  __shared__ float tile[32][33];
  int bx = blockIdx.x;            // over DDIM/32 = 24
  int by = blockIdx.y;            // over CDIM/32 = 96
  int tx = threadIdx.x & 31, ty = threadIdx.x >> 5;  // 8 rows
#pragma unroll
  for (int i = 0; i < 4; ++i) {
    int rr = ty + 8 * i;
    tile[rr][tx] = src[(size_t)(by * 32 + rr) * DDIM + bx * 32 + tx];
  }
  __syncthreads();
#pragma unroll
  for (int i = 0; i < 4; ++i) {
    int rr = ty + 8 * i;
    float v = tile[tx][rr];
    unsigned short h = bf16_rn(v);
    float lo = v - bf16_f32(h);
    size_t idx = (size_t)(bx * 32 + rr) * CDIM + by * 32 + tx;
    dhi[idx] = h;
    dlo[idx] = bf16_rn(lo);
  }
}

// ---------------- transpose+cast f32 [Z][R][Cc] -> bf16 [Z][Cc][R] ----------------
__global__ void k_transpose_cast(const float* __restrict__ src0, unsigned short* __restrict__ dst0,
                                 int R, int Cc) {
  __shared__ float tile[32][33];
  int z = blockIdx.z;
  const float* src = src0 + (size_t)z * R * Cc;
  unsigned short* dst = dst0 + (size_t)z * R * Cc;
  int bx = blockIdx.x;            // over Cc/32
  int by = blockIdx.y;            // over R/32
  int tx = threadIdx.x & 31, ty = threadIdx.x >> 5;
#pragma unroll
  for (int i = 0; i < 4; ++i) {
    int rr = ty + 8 * i;
    tile[rr][tx] = src[(size_t)(by * 32 + rr) * Cc + bx * 32 + tx];
  }
  __syncthreads();
#pragma unroll
  for (int i = 0; i < 4; ++i) {
    int rr = ty + 8 * i;
    dst[(size_t)(bx * 32 + rr) * R + by * 32 + tx] = bf16_rn(tile[tx][rr]);
  }
}

// ---------------- GEMM1: xw = hidden * pwT^T, PLAIN bf16 1-term, 32KB dbuf ----------
__launch_bounds__(256, 4)
__global__ void k_gemm1(const unsigned short* __restrict__ Ahi,  // [T][3072] bf16
                        const unsigned short* __restrict__ BTh,  // pwT_hi [768][3072]
                        float* __restrict__ Cout)                // xw [T][768]
{
  __shared__ unsigned short sA[8192], sB[8192];   // 2 bufs each (32KB total)
  int tid = threadIdx.x;
  int lane = tid & 63, wave = tid >> 6;
  int id = blockIdx.x;                       // 768 blocks
  int swz = (id & 7) * 96 + (id >> 3);       // bijective XCD swizzle (768%8==0)
  int brow = swz / 6, bcol = swz % 6;
  int row0 = brow * 128, col0 = bcol * 128;
  int wm = wave >> 1, wn = wave & 1;

  f32x4 acc[4][4];
#pragma unroll
  for (int i = 0; i < 4; ++i)
#pragma unroll
    for (int j = 0; j < 4; ++j) acc[i][j] = (f32x4){0.f, 0.f, 0.f, 0.f};

  int rsel = lane & 15, kq = lane >> 4;

  auto STAGE = [&](int kt, int b) {
    int k0 = kt * 32;
    int lbase = b * 4096;
#pragma unroll
    for (int pass = 0; pass < 2; ++pass) {
      int g = pass * 256 + tid;            // granule id 0..511
      int kg = g >> 7, r = g & 127;
      int li = lbase + (pass * 256 + wave * 64) * 8;
      glds16(Ahi + (size_t)(row0 + r) * CDIM + k0 + kg * 8, &sA[li]);
      glds16(BTh + (size_t)(col0 + r) * CDIM + k0 + kg * 8, &sB[li]);
    }
  };

  STAGE(0, 0);
  __syncthreads();
  for (int kt = 0; kt < 96; ++kt) {
    int b = kt & 1;
    if (kt + 1 < 96) STAGE(kt + 1, b ^ 1);
    int lb = b * 4096;
    bfrag af[4], bf[4];
#pragma unroll
    for (int i = 0; i < 4; ++i) {
      af[i] = *(const bfrag*)&sA[lb + (kq * 128 + wm * 64 + i * 16 + rsel) * 8];
      bf[i] = *(const bfrag*)&sB[lb + (kq * 128 + wn * 64 + i * 16 + rsel) * 8];
    }
#pragma unroll
    for (int i = 0; i < 4; ++i)
#pragma unroll
      for (int j = 0; j < 4; ++j)
        acc[i][j] = __builtin_amdgcn_mfma_f32_16x16x32_bf16(af[i], bf[j], acc[i][j], 0, 0, 0);
    __syncthreads();
  }

  int cc = lane & 15, rr = (lane >> 4) * 4;
#pragma unroll
  for (int i = 0; i < 4; ++i)
#pragma unroll
    for (int j = 0; j < 4; ++j)
#pragma unroll
      for (int r = 0; r < 4; ++r) {
        int row = row0 + wm * 64 + i * 16 + rr + r;
        int col = col0 + wn * 64 + j * 16 + cc;
        Cout[(size_t)row * DDIM + col] = acc[i][j][r];
      }
}

// ---------------- LN1 + GELU + router, wave-per-token (flag gap23 < 8e-3) ----------
__launch_bounds__(256)
__global__ void k_ln_router(const float* __restrict__ xw, const float* __restrict__ proj_b,
                            const float* __restrict__ g1, const float* __restrict__ b1v,
                            const float* __restrict__ gate_w, const float* __restrict__ gate_b,
                            unsigned short* __restrict__ seq_b16,
                            int* __restrict__ top_i, float* __restrict__ top_w,
                            int* __restrict__ amb_list, int* __restrict__ amb_count)
{
  int lane = threadIdx.x & 63;
  int t = blockIdx.x * 4 + (threadIdx.x >> 6);
  const float* xr = xw + (size_t)t * DDIM;
  float x0[12];
  float s = 0.f, s2 = 0.f;
#pragma unroll
  for (int j = 0; j < 12; ++j) {
    int d = lane + 64 * j;
    float v = xr[d] + proj_b[d];
    x0[j] = v; s += v; s2 += v * v;
  }
#pragma unroll
  for (int o = 32; o > 0; o >>= 1) { s += __shfl_xor(s, o, 64); s2 += __shfl_xor(s2, o, 64); }
  float mu = s * (1.f / DDIM);
  float rstd = rsqrtf(s2 * (1.f / DDIM) - mu * mu + 1e-5f);
  float acc8[8];
#pragma unroll
  for (int e = 0; e < 8; ++e) acc8[e] = 0.f;
#pragma unroll
  for (int j = 0; j < 12; ++j) {
    int d = lane + 64 * j;
    float y = (x0[j] - mu) * rstd * g1[d] + b1v[d];
    float ge = gelu_exact(y);
    seq_b16[(size_t)t * DDIM + d] = bf16_rn(ge);
    const float* gw = gate_w + (size_t)d * NEXP;
#pragma unroll
    for (int e = 0; e < 8; ++e) acc8[e] += ge * gw[e];
  }
#pragma unroll
  for (int e = 0; e < 8; ++e)
#pragma unroll
    for (int o = 32; o > 0; o >>= 1) acc8[e] += __shfl_xor(acc8[e], o, 64);
  if (lane == 0) {
    float lg[8];
#pragma unroll
    for (int e = 0; e < 8; ++e) lg[e] = acc8[e] + gate_b[e];
    int i0 = 0;
    for (int e = 1; e < 8; ++e) if (lg[e] > lg[i0]) i0 = e;
    int i1 = (i0 == 0) ? 1 : 0;
    for (int e = 0; e < 8; ++e) if (e != i0 && lg[e] > lg[i1]) i1 = e;
    float l2 = -1e30f;
    for (int e = 0; e < 8; ++e) if (e != i0 && e != i1 && lg[e] > l2) l2 = lg[e];
    if (lg[i1] - l2 < 8e-3f) {
      int p = atomicAdd(amb_count, 1);
      if (p < AMB_CAP) amb_list[p] = t;
    }
    float w0 = 1.f / (1.f + expf(lg[i1] - lg[i0]));
    top_i[t * 2] = i0; top_i[t * 2 + 1] = i1;
    top_w[t * 2] = w0; top_w[t * 2 + 1] = 1.f - w0;
  }
}

// ---------------- repair GEMM: 3-term split-bf16 over gathered ambiguous rows ------
__launch_bounds__(256, 4)
__global__ void k_repair(const unsigned short* __restrict__ Ahi,
                         const unsigned short* __restrict__ Alo,
                         const unsigned short* __restrict__ BTh,
                         const unsigned short* __restrict__ BTl,
                         const int* __restrict__ amb_list, const int* __restrict__ amb_count,
                         const unsigned short* __restrict__ zero_row,
                         float* __restrict__ xw_fix)   // [AMB_CAP][768]
{
  int n = *amb_count; if (n > AMB_CAP) n = AMB_CAP;
  int by = blockIdx.y;
  if (by * 128 >= n) return;
  int bx = blockIdx.x;                 // 0..5
  int col0 = bx * 128;
  __shared__ unsigned short sAh[4096], sAl[4096], sBh[4096], sBl[4096];
  __shared__ int tk[128];
  int tid = threadIdx.x, lane = tid & 63, wave = tid >> 6;
  if (tid < 128) tk[tid] = (by * 128 + tid < n) ? amb_list[by * 128 + tid] : -1;
  __syncthreads();
  int wm = wave >> 1, wn = wave & 1;
  f32x4 acc[4][4];
#pragma unroll
  for (int i = 0; i < 4; ++i)
#pragma unroll
    for (int j = 0; j < 4; ++j) acc[i][j] = (f32x4){0.f, 0.f, 0.f, 0.f};
  int rsel = lane & 15, kq = lane >> 4;

  for (int kt = 0; kt < 96; ++kt) {
    int k0 = kt * 32;
#pragma unroll
    for (int pass = 0; pass < 2; ++pass) {
      int g = pass * 256 + tid;
      int kg = g >> 7, r = g & 127;
      int tok = tk[r];
      size_t aoff = (size_t)tok * CDIM + k0 + kg * 8;
      const unsigned short* ah = (tok >= 0) ? (Ahi + aoff) : zero_row;
      const unsigned short* al = (tok >= 0) ? (Alo + aoff) : zero_row;
      size_t boff = (size_t)(col0 + r) * CDIM + k0 + kg * 8;
      int li = (pass * 256 + wave * 64) * 8;
      glds16(ah, &sAh[li]);
      glds16(al, &sAl[li]);
      glds16(BTh + boff, &sBh[li]);
      glds16(BTl + boff, &sBl[li]);
    }
    __syncthreads();
    bfrag ah[4], al[4], bh[4], bl[4];
#pragma unroll
    for (int i = 0; i < 4; ++i) {
      int ra = wm * 64 + i * 16 + rsel;
      ah[i] = *(const bfrag*)&sAh[(kq * 128 + ra) * 8];
      al[i] = *(const bfrag*)&sAl[(kq * 128 + ra) * 8];
      int cb = wn * 64 + i * 16 + rsel;
      bh[i] = *(const bfrag*)&sBh[(kq * 128 + cb) * 8];
      bl[i] = *(const bfrag*)&sBl[(kq * 128 + cb) * 8];
    }
#pragma unroll
    for (int i = 0; i < 4; ++i)
#pragma unroll
      for (int j = 0; j < 4; ++j) {
        acc[i][j] = __builtin_amdgcn_mfma_f32_16x16x32_bf16(ah[i], bh[j], acc[i][j], 0, 0, 0);
        acc[i][j] = __builtin_amdgcn_mfma_f32_16x16x32_bf16(ah[i], bl[j], acc[i][j], 0, 0, 0);
        acc[i][j] = __builtin_amdgcn_mfma_f32_16x16x32_bf16(al[i], bh[j], acc[i][j], 0, 0, 0);
      }
    __syncthreads();
  }
  int cc = lane & 15, rr = (lane >> 4) * 4;
#pragma unroll
  for (int i = 0; i < 4; ++i)
#pragma unroll
    for (int j = 0; j < 4; ++j)
#pragma unroll
      for (int r = 0; r < 4; ++r) {
        int row = by * 128 + wm * 64 + i * 16 + rr + r;   // slot index
        int col = col0 + wn * 64 + j * 16 + cc;
        xw_fix[(size_t)row * DDIM + col] = acc[i][j][r];
      }
}

// ---------------- fix2: re-route ambiguous tokens from precise xw_fix -------------
__launch_bounds__(256)
__global__ void k_fix2(const float* __restrict__ xw_fix, const float* __restrict__ proj_b,
                       const float* __restrict__ g1, const float* __restrict__ b1v,
                       const float* __restrict__ gate_w, const float* __restrict__ gate_b,
                       const int* __restrict__ amb_list, const int* __restrict__ amb_count,
                       int* __restrict__ top_i, float* __restrict__ top_w,
                       int* __restrict__ amb2_list, int* __restrict__ amb2_count)
{
  int n = *amb_count; if (n > AMB_CAP) n = AMB_CAP;
  int lane = threadIdx.x & 63;
  int slot = blockIdx.x * 4 + (threadIdx.x >> 6);
  if (slot >= n) return;
  int t = amb_list[slot];
  const float* xr = xw_fix + (size_t)slot * DDIM;
  float x0[12];
  float s = 0.f, s2 = 0.f;
#pragma unroll
  for (int j = 0; j < 12; ++j) {
    int d = lane + 64 * j;
    float v = xr[d] + proj_b[d];
    x0[j] = v; s += v; s2 += v * v;
  }
#pragma unroll
  for (int o = 32; o > 0; o >>= 1) { s += __shfl_xor(s, o, 64); s2 += __shfl_xor(s2, o, 64); }
  float mu = s * (1.f / DDIM);
  float rstd = rsqrtf(s2 * (1.f / DDIM) - mu * mu + 1e-5f);
  float acc8[8];
#pragma unroll
  for (int e = 0; e < 8; ++e) acc8[e] = 0.f;
#pragma unroll
  for (int j = 0; j < 12; ++j) {
    int d = lane + 64 * j;
    float y = (x0[j] - mu) * rstd * g1[d] + b1v[d];
    float ge = gelu_exact(y);
    const float* gw = gate_w + (size_t)d * NEXP;
#pragma unroll
    for (int e = 0; e < 8; ++e) acc8[e] += ge * gw[e];
  }
#pragma unroll
  for (int e = 0; e < 8; ++e)
#pragma unroll
    for (int o = 32; o > 0; o >>= 1) acc8[e] += __shfl_xor(acc8[e], o, 64);
  if (lane == 0) {
    float lg[8];
#pragma unroll
    for (int e = 0; e < 8; ++e) lg[e] = acc8[e] + gate_b[e];
    int i0 = 0;
    for (int e = 1; e < 8; ++e) if (lg[e] > lg[i0]) i0 = e;
    int i1 = (i0 == 0) ? 1 : 0;
    for (int e = 0; e < 8; ++e) if (e != i0 && lg[e] > lg[i1]) i1 = e;
    float l2 = -1e30f;
    for (int e = 0; e < 8; ++e) if (e != i0 && e != i1 && lg[e] > l2) l2 = lg[e];
    if (lg[i1] - l2 < 2e-4f) {
      int p = atomicAdd(amb2_count, 1);
      if (p < AMB_CAP) amb2_list[p] = t;
    }
    float w0 = 1.f / (1.f + expf(lg[i1] - lg[i0]));
    top_i[t * 2] = i0; top_i[t * 2 + 1] = i1;
    top_w[t * 2] = w0; top_w[t * 2 + 1] = 1.f - w0;
  }
}

// ---------------- f64 router fix for near-tie tokens (register-batched ILP) ----------------
__launch_bounds__(256, 1)
__global__ void k_router_fix(const float* __restrict__ hidden, const float* __restrict__ proj_w,
                             const float* __restrict__ proj_b, const float* __restrict__ g1,
                             const float* __restrict__ b1v, const float* __restrict__ gate_w,
                             const float* __restrict__ gate_b,
                             const int* __restrict__ amb_list, const int* __restrict__ amb_count,
                             int* __restrict__ top_i, float* __restrict__ top_w)
{
  __shared__ float hrow[CDIM];
  __shared__ double redA[4], redB[4], red8[4][8];
  int tid = threadIdx.x, lane = tid & 63, wave = tid >> 6;
  int n = *amb_count; if (n > AMB_CAP) n = AMB_CAP;
  for (int ii = blockIdx.x; ii < n; ii += gridDim.x) {
    int t = amb_list[ii];
    __syncthreads();   // guard hrow/red reuse across loop iterations
    for (int c = tid * 4; c < CDIM; c += 1024)
      *(fvec4*)&hrow[c] = *(const fvec4*)(hidden + (size_t)t * CDIM + c);
    __syncthreads();
    double a0a = 0.0, a0b = 0.0, a1a = 0.0, a1b = 0.0, a2a = 0.0, a2b = 0.0;
    for (int c0 = 0; c0 < CDIM; c0 += 16) {
      float w0r[16], w1r[16], w2r[16];
      const float* wp = proj_w + (size_t)c0 * DDIM + tid;
#pragma unroll
      for (int u = 0; u < 16; ++u) {
        w0r[u] = wp[u * DDIM];
        w1r[u] = wp[u * DDIM + 256];
        w2r[u] = wp[u * DDIM + 512];
      }
#pragma unroll
      for (int u = 0; u < 16; ++u) {
        double h = (double)hrow[c0 + u];
        if (u & 1) { a0b += h * (double)w0r[u]; a1b += h * (double)w1r[u]; a2b += h * (double)w2r[u]; }
        else       { a0a += h * (double)w0r[u]; a1a += h * (double)w1r[u]; a2a += h * (double)w2r[u]; }
      }
    }
    double x[3]; double s = 0.0, s2 = 0.0;
    x[0] = a0a + a0b + (double)proj_b[tid];
    x[1] = a1a + a1b + (double)proj_b[tid + 256];
    x[2] = a2a + a2b + (double)proj_b[tid + 512];
#pragma unroll
    for (int j = 0; j < 3; ++j) { s += x[j]; s2 += x[j] * x[j]; }
#pragma unroll
    for (int o = 32; o > 0; o >>= 1) { s += __shfl_down(s, o, 64); s2 += __shfl_down(s2, o, 64); }
    if (lane == 0) { redA[wave] = s; redB[wave] = s2; }
    __syncthreads();
    double mu = (redA[0] + redA[1] + redA[2] + redA[3]) / DDIM;
    double ms = (redB[0] + redB[1] + redB[2] + redB[3]) / DDIM;
    double rstd = 1.0 / sqrt(ms - mu * mu + 1e-5);
    double a8[8];
#pragma unroll
    for (int e = 0; e < 8; ++e) a8[e] = 0.0;
#pragma unroll
    for (int j = 0; j < 3; ++j) {
      int d = tid + 256 * j;
      double y = (x[j] - mu) * rstd * (double)g1[d] + (double)b1v[d];
      double ge = 0.5 * y * (1.0 + erf(y * 0.7071067811865475244));
#pragma unroll
      for (int e = 0; e < 8; ++e) a8[e] += ge * (double)gate_w[(size_t)d * NEXP + e];
    }
#pragma unroll
    for (int e = 0; e < 8; ++e)
#pragma unroll
      for (int o = 32; o > 0; o >>= 1) a8[e] += __shfl_down(a8[e], o, 64);
    if (lane == 0) {
#pragma unroll
      for (int e = 0; e < 8; ++e) red8[wave][e] = a8[e];
    }
    __syncthreads();
    if (tid == 0) {
      double lg[8];
#pragma unroll
      for (int e = 0; e < 8; ++e)
        lg[e] = red8[0][e] + red8[1][e] + red8[2][e] + red8[3][e] + (double)gate_b[e];
      int i0 = 0;
      for (int e = 1; e < 8; ++e) if (lg[e] > lg[i0]) i0 = e;
      int i1 = (i0 == 0) ? 1 : 0;
      for (int e = 0; e < 8; ++e) if (e != i0 && e != i1 && lg[e] > lg[i1]) i1 = e;
      double w0 = 1.0 / (1.0 + exp(lg[i1] - lg[i0]));
      top_i[t * 2] = i0; top_i[t * 2 + 1] = i1;
      top_w[t * 2] = (float)w0; top_w[t * 2 + 1] = (float)(1.0 - w0);
    }
  }
}

// ---------------- histogram of final top_i (LDS privatized) ----------------
__global__ void k_count(const int* __restrict__ top_i, int* __restrict__ counts) {
  __shared__ int h[NEXP];
  int tid = threadIdx.x;
  if (tid < NEXP) h[tid] = 0;
  __syncthreads();
  for (int i = blockIdx.x * 256 + tid; i < 2 * T_TOK; i += 64 * 256)
    atomicAdd(&h[top_i[i]], 1);
  __syncthreads();
  if (tid < NEXP) atomicAdd(&counts[tid], h[tid]);
}

// ---------------- offsets (single thread) ----------------
__global__ void k_offsets(const int* __restrict__ counts, int* __restrict__ seg_start,
                          int* __restrict__ padded_total, int* __restrict__ tile_expert) {
  if (threadIdx.x != 0 || blockIdx.x != 0) return;
  int st[NEXP], en[NEXP];
  int s = 0;
  for (int e = 0; e < NEXP; ++e) {
    st[e] = s; seg_start[e] = s;
    s += (counts[e] + 127) & ~127;
    en[e] = s;
  }
  *padded_total = s;
  int nt = s >> 7;
  for (int x = 0; x < nt; ++x) {
    int r = x << 7, e = 0;
    for (int q = 0; q < NEXP; ++q) if (r >= st[q] && r < en[q]) e = q;
    tile_expert[x] = e;
  }
}

// ---------------- scatter: block-aggregated cursors ----------------
__global__ void k_scatter(const int* __restrict__ top_i, const int* __restrict__ seg_start,
                          int* __restrict__ cursors, int* __restrict__ token_list,
                          int* __restrict__ slot_of) {
  __shared__ int lc[NEXP];
  __shared__ int lbase[NEXP];
  int tid = threadIdx.x;
  int t = blockIdx.x * 256 + tid;
  if (tid < NEXP) lc[tid] = 0;
  __syncthreads();
  int e0 = top_i[t * 2], e1 = top_i[t * 2 + 1];
  int o0 = atomicAdd(&lc[e0], 1);
  int o1 = atomicAdd(&lc[e1], 1);
  __syncthreads();
  if (tid < NEXP) lbase[tid] = atomicAdd(&cursors[tid << 4], lc[tid]);
  __syncthreads();
  int p0 = seg_start[e0] + lbase[e0] + o0;
  int p1 = seg_start[e1] + lbase[e1] + o1;
  token_list[p0] = t;
  token_list[p1] = t;
  slot_of[t * 2] = p0;
  slot_of[t * 2 + 1] = p1;
}

// ---------------- GEMM2: h = gelu(gather(seq)*w1 + b1), bf16, dbuf ----------------
__launch_bounds__(256, 4)
__global__ void k_gemm2(const unsigned short* __restrict__ Abase,  // seq_bf16 [T][768]
                        const unsigned short* __restrict__ w1T,    // [E][1024][768]
                        const float* __restrict__ b1,              // [E][1024]
                        const int* __restrict__ token_list,
                        const int* __restrict__ tile_expert,
                        const int* __restrict__ padded_total,
                        const unsigned short* __restrict__ zero_row,
                        unsigned short* __restrict__ hbuf)         // [NSLOT][1024]
{
  int by = blockIdx.y;
  if (by * 128 >= *padded_total) return;
  int bx = blockIdx.x;                    // 0..7
  int e = tile_expert[by];
  __shared__ unsigned short sA[8192], sB[8192];   // 2 bufs each
  __shared__ int tk[128];
  int tid = threadIdx.x, lane = tid & 63, wave = tid >> 6;
  if (tid < 128) tk[tid] = token_list[by * 128 + tid];
  __syncthreads();
  int col0 = bx * 128;
  int wm = wave >> 1, wn = wave & 1;
  f32x4 acc[4][4];
#pragma unroll
  for (int i = 0; i < 4; ++i)
#pragma unroll
    for (int j = 0; j < 4; ++j) acc[i][j] = (f32x4){0.f, 0.f, 0.f, 0.f};
  const unsigned short* Bbase = w1T + ((size_t)e * HDIM + col0) * DDIM;
  int rsel = lane & 15, kq = lane >> 4;

  auto STAGE = [&](int kt, int b) {
    int k0 = kt * 32;
    int lbase2 = b * 4096;
#pragma unroll
    for (int pass = 0; pass < 2; ++pass) {
      int g = pass * 256 + tid;
      int kg = g >> 7, r = g & 127;
      int tok = tk[r];
      const unsigned short* asrc =
          (tok >= 0) ? (Abase + (size_t)tok * DDIM + k0 + kg * 8) : zero_row;
      int li = lbase2 + (pass * 256 + wave * 64) * 8;
      glds16(asrc, &sA[li]);
      glds16(Bbase + (size_t)r * DDIM + k0 + kg * 8, &sB[li]);
    }
  };

  STAGE(0, 0);
  __syncthreads();
  for (int kt = 0; kt < 24; ++kt) {
    int b = kt & 1;
    if (kt + 1 < 24) STAGE(kt + 1, b ^ 1);
    int lb = b * 4096;
    bfrag af[4], bf[4];
#pragma unroll
    for (int i = 0; i < 4; ++i) {
      af[i] = *(const bfrag*)&sA[lb + (kq * 128 + wm * 64 + i * 16 + rsel) * 8];
      bf[i] = *(const bfrag*)&sB[lb + (kq * 128 + wn * 64 + i * 16 + rsel) * 8];
    }
#pragma unroll
    for (int i = 0; i < 4; ++i)
#pragma unroll
      for (int j = 0; j < 4; ++j)
        acc[i][j] = __builtin_amdgcn_mfma_f32_16x16x32_bf16(af[i], bf[j], acc[i][j], 0, 0, 0);
    __syncthreads();
  }
  int cc = lane & 15, rr = (lane >> 4) * 4;
#pragma unroll
  for (int i = 0; i < 4; ++i)
#pragma unroll
    for (int j = 0; j < 4; ++j)
#pragma unroll
      for (int r = 0; r < 4; ++r) {
        int row = by * 128 + wm * 64 + i * 16 + rr + r;
        int col = col0 + wn * 64 + j * 16 + cc;
        float x = acc[i][j][r] + b1[(size_t)e * HDIM + col];
        hbuf[(size_t)row * HDIM + col] = bf16_rn(gelu_exact(x));
      }
}

// ---------------- GEMM3: eo = h*w2 + b2, bf16 -> f32, dbuf ----------------
__launch_bounds__(256, 4)
__global__ void k_gemm3(const unsigned short* __restrict__ hbuf,  // [NSLOT][1024]
                        const unsigned short* __restrict__ w2T,   // [E][768][1024]
                        const float* __restrict__ b2,              // [E][768]
                        const int* __restrict__ tile_expert,
                        const int* __restrict__ padded_total,
                        float* __restrict__ eo)                   // [NSLOT][768]
{
  int by = blockIdx.y;
  if (by * 128 >= *padded_total) return;
  int bx = blockIdx.x;                    // 0..5
  int e = tile_expert[by];
  __shared__ unsigned short sA[8192], sB[8192];
  int tid = threadIdx.x, lane = tid & 63, wave = tid >> 6;
  int col0 = bx * 128;
  int wm = wave >> 1, wn = wave & 1;
  f32x4 acc[4][4];
#pragma unroll
  for (int i = 0; i < 4; ++i)
#pragma unroll
    for (int j = 0; j < 4; ++j) acc[i][j] = (f32x4){0.f, 0.f, 0.f, 0.f};
  const unsigned short* Bbase = w2T + ((size_t)e * DDIM + col0) * HDIM;
  int rsel = lane & 15, kq = lane >> 4;

  auto STAGE = [&](int kt, int b) {
    int k0 = kt * 32;
    int lbase2 = b * 4096;
#pragma unroll
    for (int pass = 0; pass < 2; ++pass) {
      int g = pass * 256 + tid;
      int kg = g >> 7, r = g & 127;
      int li = lbase2 + (pass * 256 + wave * 64) * 8;
      glds16(hbuf + (size_t)(by * 128 + r) * HDIM + k0 + kg * 8, &sA[li]);
      glds16(Bbase + (size_t)r * HDIM + k0 + kg * 8, &sB[li]);
    }
  };

  STAGE(0, 0);
  __syncthreads();
  for (int kt = 0; kt < 32; ++kt) {
    int b = kt & 1;
    if (kt + 1 < 32) STAGE(kt + 1, b ^ 1);
    int lb = b * 4096;
    bfrag af[4], bf[4];
#pragma unroll
    for (int i = 0; i < 4; ++i) {
      af[i] = *(const bfrag*)&sA[lb + (kq * 128 + wm * 64 + i * 16 + rsel) * 8];
      bf[i] = *(const bfrag*)&sB[lb + (kq * 128 + wn * 64 + i * 16 + rsel) * 8];
    }
#pragma unroll
    for (int i = 0; i < 4; ++i)
#pragma unroll
      for (int j = 0; j < 4; ++j)
        acc[i][j] = __builtin_amdgcn_mfma_f32_16x16x32_bf16(af[i], bf[j], acc[i][j], 0, 0, 0);
    __syncthreads();
  }
  int cc = lane & 15, rr = (lane >> 4) * 4;
#pragma unroll
  for (int i = 0; i < 4; ++i)
#pragma unroll
    for (int j = 0; j < 4; ++j)
#pragma unroll
      for (int r = 0; r < 4; ++r) {
        int row = by * 128 + wm * 64 + i * 16 + rr + r;
        int col = col0 + wn * 64 + j * 16 + cc;
        eo[(size_t)row * DDIM + col] = acc[i][j][r] + b2[(size_t)e * DDIM + col];
      }
}

// ---------------- combine + LN2 + classifier, wave-per-token ----------------
__launch_bounds__(256)
__global__ void k_combine(const float* __restrict__ eo, const unsigned short* __restrict__ seqb,
                          const int* __restrict__ slot_of, const float* __restrict__ top_w,
                          const float* __restrict__ g2, const float* __restrict__ b2v,
                          const float* __restrict__ cls_w, const float* __restrict__ cls_b,
                          float* __restrict__ out)
{
  int lane = threadIdx.x & 63;
  int t = blockIdx.x * 4 + (threadIdx.x >> 6);
  int s0 = slot_of[t * 2], s1 = slot_of[t * 2 + 1];
  float w0 = top_w[t * 2], w1 = top_w[t * 2 + 1];
  const float* p0 = eo + (size_t)s0 * DDIM;
  const float* p1 = eo + (size_t)s1 * DDIM;
  const unsigned short* sq = seqb + (size_t)t * DDIM;
  float m[12];
  float s = 0.f, s2 = 0.f;
#pragma unroll
  for (int j = 0; j < 12; ++j) {
    int d = lane + 64 * j;
    float v = w0 * p0[d] + w1 * p1[d] + bf16_f32(sq[d]);
    m[j] = v; s += v; s2 += v * v;
  }
#pragma unroll
  for (int o = 32; o > 0; o >>= 1) { s += __shfl_xor(s, o, 64); s2 += __shfl_xor(s2, o, 64); }
  float mu = s * (1.f / DDIM);
  float rstd = rsqrtf(s2 * (1.f / DDIM) - mu * mu + 1e-5f);
  float l0 = 0.f, l1 = 0.f;
#pragma unroll
  for (int j = 0; j < 12; ++j) {
    int d = lane + 64 * j;
    float y = (m[j] - mu) * rstd * g2[d] + b2v[d];
    l0 += y * cls_w[d * 2];
    l1 += y * cls_w[d * 2 + 1];
  }
#pragma unroll
  for (int o = 32; o > 0; o >>= 1) { l0 += __shfl_xor(l0, o, 64); l1 += __shfl_xor(l1, o, 64); }
  if (lane == 0) {
    out[(size_t)t * 2] = l0 + cls_b[0];
    out[(size_t)t * 2 + 1] = l1 + cls_b[1];
  }
}

extern "C" void kernel_launch(void* const* d_in, const int* in_sizes, int n_in,
                              void* d_out, int out_size, void* d_ws, size_t ws_size,
                              hipStream_t stream) {
  const float* hidden = (const float*)d_in[0];
  const float* proj_w = (const float*)d_in[1];
  const float* proj_b = (const float*)d_in[2];
  const float* ln1_g  = (const float*)d_in[3];
  const float* ln1_b  = (const float*)d_in[4];
  const float* gate_w = (const float*)d_in[5];
  const float* gate_b = (const float*)d_in[6];
  const float* w1     = (const float*)d_in[7];
  const float* b1     = (const float*)d_in[8];
  const float* w2     = (const float*)d_in[9];
  const float* b2     = (const float*)d_in[10];
  const float* ln2_g  = (const float*)d_in[11];
  const float* ln2_b  = (const float*)d_in[12];
  const float* cls_w  = (const float*)d_in[13];
  const float* cls_b  = (const float*)d_in[14];
  float* out = (float*)d_out;

  char* base = (char*)d_ws;
  size_t off = 0;
  auto alloc = [&](size_t b) -> void* {
    void* p = base + off;
    off += (b + 255) & ~(size_t)255;
    return p;
  };
  // permanent buffers (live across the repair chain)
  unsigned short* pwT_hi = (unsigned short*)alloc((size_t)DDIM * CDIM * 2);
  unsigned short* pwT_lo = (unsigned short*)alloc((size_t)DDIM * CDIM * 2);
  unsigned short* w1T    = (unsigned short*)alloc((size_t)NEXP * HDIM * DDIM * 2);
  unsigned short* w2T    = (unsigned short*)alloc((size_t)NEXP * DDIM * HDIM * 2);
  float* xw              = (float*)alloc((size_t)T_TOK * DDIM * 4);
  float* xw_fix          = (float*)alloc((size_t)AMB_CAP * DDIM * 4);
  unsigned short* seqb   = (unsigned short*)alloc((size_t)T_TOK * DDIM * 2);
  int* top_i             = (int*)alloc((size_t)T_TOK * 2 * 4);
  float* top_w           = (float*)alloc((size_t)T_TOK * 2 * 4);
  int* slot_of           = (int*)alloc((size_t)T_TOK * 2 * 4);
  int* amb_list          = (int*)alloc((size_t)AMB_CAP * 4);
  int* amb2_list         = (int*)alloc((size_t)AMB_CAP * 4);
  int* token_list        = (int*)alloc((size_t)NSLOT * 4);
  int* counts            = (int*)alloc(256);
  int* cursors           = (int*)alloc(512);
  int* seg_start         = (int*)alloc(256);
  int* padded_total      = (int*)alloc(256);
  int* tile_expert       = (int*)alloc((size_t)MAXTILE * 4);
  unsigned short* zero_row = (unsigned short*)alloc(2048);
  int* amb_count         = (int*)alloc(256);
  int* amb2_count        = (int*)alloc(256);
  // aliased pool: Ahi/Alo live until k_repair completes; hbuf/eo written after.
  size_t poolBytes = 2 * (size_t)T_TOK * CDIM * 2;    // 201.3 MB
  char* pool = (char*)alloc(poolBytes);
  unsigned short* Ahi = (unsigned short*)pool;
  unsigned short* Alo = Ahi + (size_t)T_TOK * CDIM;
  size_t poff = 0;
  auto palloc = [&](size_t b) -> void* {
    void* p = pool + poff;
    poff += (b + 255) & ~(size_t)255;
    return p;
  };
  unsigned short* hbuf   = (unsigned short*)palloc((size_t)NSLOT * HDIM * 2);
  float* eo              = (float*)palloc((size_t)NSLOT * DDIM * 4);
  (void)ws_size; (void)in_sizes; (void)n_in; (void)out_size;

  k_init<<<64, 256, 0, stream>>>(token_list, counts, cursors, zero_row, amb_count, amb2_count);
  k_split_hidden<<<(T_TOK * CDIM) / 2048, 256, 0, stream>>>(hidden, Ahi, Alo);
  k_transpose_split<<<dim3(24, 96), 256, 0, stream>>>(proj_w, pwT_hi, pwT_lo);
  k_transpose_cast<<<dim3(32, 24, 8), 256, 0, stream>>>(w1, w1T, DDIM, HDIM);
  k_transpose_cast<<<dim3(24, 32, 8), 256, 0, stream>>>(w2, w2T, HDIM, DDIM);
  k_gemm1<<<768, 256, 0, stream>>>(Ahi, pwT_hi, xw);
  k_ln_router<<<T_TOK / 4, 256, 0, stream>>>(xw, proj_b, ln1_g, ln1_b, gate_w, gate_b,
                                             seqb, top_i, top_w, amb_list, amb_count);
  k_repair<<<dim3(6, AMB_CAP / 128), 256, 0, stream>>>(Ahi, Alo, pwT_hi, pwT_lo,
                                                       amb_list, amb_count, zero_row, xw_fix);
  k_fix2<<<AMB_CAP / 4, 256, 0, stream>>>(xw_fix, proj_b, ln1_g, ln1_b, gate_w, gate_b,
                                          amb_list, amb_count, top_i, top_w,
                                          amb2_list, amb2_count);
  k_router_fix<<<256, 256, 0, stream>>>(hidden, proj_w, proj_b, ln1_g, ln1_b, gate_w, gate_b,
                                        amb2_list, amb2_count, top_i, top_w);
  k_count<<<64, 256, 0, stream>>>(top_i, counts);
  k_offsets<<<1, 64, 0, stream>>>(counts, seg_start, padded_total, tile_expert);
  k_scatter<<<64, 256, 0, stream>>>(top_i, seg_start, cursors, token_list, slot_of);
  k_gemm2<<<dim3(8, MAXTILE), 256, 0, stream>>>(seqb, w1T, b1, token_list, tile_expert,
                                                padded_total, zero_row, hbuf);
  k_gemm3<<<dim3(6, MAXTILE), 256, 0, stream>>>(hbuf, w2T, b2, tile_expert, padded_total, eo);
  k_combine<<<T_TOK / 4, 256, 0, stream>>>(eo, seqb, slot_of, top_w, ln2_g, ln2_b,
                                           cls_w, cls_b, out);
}